// Round 1
// baseline (234.473 us; speedup 1.0000x reference)
//
#include <hip/hip_runtime.h>
#include <hip/hip_bf16.h>

// SNN IF scan: for each neuron (B*C*H*W of them), mem=0.5*th; for t in 0..3:
// mem += x[t]; spike = (mem>=th)?th:0; mem -= spike; out[t]=spike.
// Memory-bound: 134 MB in + 134 MB out. One thread = one float4 of neurons,
// carries mem in registers across the T=4 scan (stride n4 between timesteps).

#define T_STEPS 4

__global__ __launch_bounds__(256) void IF_18622978195596_kernel(
    const float4* __restrict__ x, const float* __restrict__ thresh_p,
    float4* __restrict__ out, int n4) {
    int i = blockIdx.x * blockDim.x + threadIdx.x;
    if (i >= n4) return;
    const float th = *thresh_p;
    float4 mem = make_float4(0.5f * th, 0.5f * th, 0.5f * th, 0.5f * th);
#pragma unroll
    for (int t = 0; t < T_STEPS; ++t) {
        size_t idx = (size_t)t * n4 + i;
        float4 xv = x[idx];
        mem.x += xv.x; mem.y += xv.y; mem.z += xv.z; mem.w += xv.w;
        float sx = (mem.x >= th) ? th : 0.0f;
        float sy = (mem.y >= th) ? th : 0.0f;
        float sz = (mem.z >= th) ? th : 0.0f;
        float sw = (mem.w >= th) ? th : 0.0f;
        mem.x -= sx; mem.y -= sy; mem.z -= sz; mem.w -= sw;
        out[idx] = make_float4(sx, sy, sz, sw);
    }
}

extern "C" void kernel_launch(void* const* d_in, const int* in_sizes, int n_in,
                              void* d_out, int out_size, void* d_ws, size_t ws_size,
                              hipStream_t stream) {
    const float* x = (const float*)d_in[0];
    const float* thresh = (const float*)d_in[1];
    // d_in[2] is T (device int); shape is fixed at T=4 for this problem.
    float* out = (float*)d_out;

    int total = in_sizes[0];              // 33,554,432 floats
    int n_per_t = total / T_STEPS;        // 8,388,608 neurons
    int n4 = n_per_t / 4;                 // 2,097,152 float4 per timestep

    int block = 256;
    int grid = (n4 + block - 1) / block;  // 8192 blocks
    IF_18622978195596_kernel<<<grid, block, 0, stream>>>(
        (const float4*)x, thresh, (float4*)out, n4);
}